// Round 1
// baseline (152.517 us; speedup 1.0000x reference)
//
#include <hip/hip_runtime.h>

#define HW    4096
#define CIN   32

// scale in log2 domain: (1/sqrt(NCLASS)) * log2(e); NCLASS = 2
#define SCALE2 (0.70710678118654752f * 1.44269504088896340f)

// ---------------- Kernel A: 1x1 conv projections f1 = W1*x+b1, f2 = W2*x+b2
__global__ __launch_bounds__(256) void proj_kernel(
        const float* __restrict__ feat,
        const float* __restrict__ w1, const float* __restrict__ b1,
        const float* __restrict__ w2, const float* __restrict__ b2,
        float2* __restrict__ f1v, float2* __restrict__ f2v) {
    int gid = blockIdx.x * 256 + threadIdx.x;       // 16384 = 4 * 4096
    int n = gid >> 12;
    int p = gid & 4095;
    const float* fbase = feat + (size_t)n * CIN * HW + p;
    float a10 = 0.f, a11 = 0.f, a20 = 0.f, a21 = 0.f;
#pragma unroll
    for (int c = 0; c < CIN; ++c) {
        float v = fbase[(size_t)c * HW];
        a10 += v * w1[c];            // w1[0][c]
        a11 += v * w1[CIN + c];      // w1[1][c]
        a20 += v * w2[c];
        a21 += v * w2[CIN + c];
    }
    f1v[gid] = make_float2(a10 + b1[0], a11 + b1[1]);
    f2v[gid] = make_float2(a20 + b2[0], a21 + b2[1]);
}

// ---------------- Kernel B: per-row (p) softmax stats over q, store {m, V0/l, V1/l}
__global__ __launch_bounds__(256) void rowstats_kernel(
        const float2* __restrict__ f1v, const float2* __restrict__ f2v,
        const float* __restrict__ outv, float4* __restrict__ stats) {
    __shared__ float sm[4][64];
    __shared__ float sl[4][64];
    int tid = threadIdx.x;
    int pl = tid & 63;
    int slice = __builtin_amdgcn_readfirstlane(tid >> 6);  // wave-uniform -> SGPR
    int n = blockIdx.x >> 6;                 // 64 blocks per batch
    int p = ((blockIdx.x & 63) << 6) + pl;
    int base = n * HW;

    float2 f1p = f1v[base + p];
    float f10 = f1p.x * SCALE2, f11 = f1p.y * SCALE2;
    const float2* f2b = f2v + base + slice * 1024;   // uniform base -> s_loads

    // pass 1: max over this slice's 1024 q (4 independent max chains)
    float m0 = -1e30f, m1 = -1e30f, m2 = -1e30f, m3 = -1e30f;
    for (int q = 0; q < 1024; q += 4) {
        float2 a = f2b[q + 0], b = f2b[q + 1], c = f2b[q + 2], d = f2b[q + 3];
        m0 = fmaxf(m0, f10 * a.x + f11 * a.y);
        m1 = fmaxf(m1, f10 * b.x + f11 * b.y);
        m2 = fmaxf(m2, f10 * c.x + f11 * c.y);
        m3 = fmaxf(m3, f10 * d.x + f11 * d.y);
    }
    float m = fmaxf(fmaxf(m0, m1), fmaxf(m2, m3));

    // pass 2: l = sum 2^(t - m)
    float l0 = 0.f, l1 = 0.f, l2 = 0.f, l3 = 0.f;
    for (int q = 0; q < 1024; q += 4) {
        float2 a = f2b[q + 0], b = f2b[q + 1], c = f2b[q + 2], d = f2b[q + 3];
        l0 += exp2f(f10 * a.x + f11 * a.y - m);
        l1 += exp2f(f10 * b.x + f11 * b.y - m);
        l2 += exp2f(f10 * c.x + f11 * c.y - m);
        l3 += exp2f(f10 * d.x + f11 * d.y - m);
    }
    float l = (l0 + l1) + (l2 + l3);

    sm[slice][pl] = m;
    sl[slice][pl] = l;
    __syncthreads();
    if (tid < 64) {
        float mm = fmaxf(fmaxf(sm[0][pl], sm[1][pl]), fmaxf(sm[2][pl], sm[3][pl]));
        float ll = sl[0][pl] * exp2f(sm[0][pl] - mm)
                 + sl[1][pl] * exp2f(sm[1][pl] - mm)
                 + sl[2][pl] * exp2f(sm[2][pl] - mm)
                 + sl[3][pl] * exp2f(sm[3][pl] - mm);
        float inv = 1.0f / ll;
        float v0 = outv[(n * 2 + 0) * HW + p];
        float v1 = outv[(n * 2 + 1) * HW + p];
        stats[base + p] = make_float4(mm, v0 * inv, v1 * inv, 0.f);
    }
}

// ---------------- Kernel C: o[c,q] = sum_p (V[c,p]/l[p]) * 2^(t[p,q]-m[p])
__global__ __launch_bounds__(256) void colout_kernel(
        const float2* __restrict__ f1v, const float2* __restrict__ f2v,
        const float4* __restrict__ stats, float* __restrict__ o) {
    __shared__ float so0[4][64];
    __shared__ float so1[4][64];
    int tid = threadIdx.x;
    int ql = tid & 63;
    int slice = __builtin_amdgcn_readfirstlane(tid >> 6);
    int n = blockIdx.x >> 6;
    int q = ((blockIdx.x & 63) << 6) + ql;
    int base = n * HW;

    float2 f2q = f2v[base + q];
    float g0 = f2q.x * SCALE2, g1 = f2q.y * SCALE2;
    const float2* f1b = f1v + base + slice * 1024;      // uniform -> s_loads
    const float4* stb = stats + base + slice * 1024;    // uniform -> s_loads

    float o00 = 0.f, o01 = 0.f, o10 = 0.f, o11 = 0.f;
    for (int p = 0; p < 1024; p += 2) {
        float2 fa = f1b[p], fb = f1b[p + 1];
        float4 sa = stb[p], sb = stb[p + 1];
        float ea = exp2f(g0 * fa.x + g1 * fa.y - sa.x);
        float eb = exp2f(g0 * fb.x + g1 * fb.y - sb.x);
        o00 += sa.y * ea;
        o01 += sa.z * ea;
        o10 += sb.y * eb;
        o11 += sb.z * eb;
    }
    so0[slice][ql] = o00 + o10;
    so1[slice][ql] = o01 + o11;
    __syncthreads();
    if (tid < 64) {
        float r0 = (so0[0][ql] + so0[1][ql]) + (so0[2][ql] + so0[3][ql]);
        float r1 = (so1[0][ql] + so1[1][ql]) + (so1[2][ql] + so1[3][ql]);
        o[(n * 2 + 0) * HW + q] = r0;
        o[(n * 2 + 1) * HW + q] = r1;
    }
}

extern "C" void kernel_launch(void* const* d_in, const int* in_sizes, int n_in,
                              void* d_out, int out_size, void* d_ws, size_t ws_size,
                              hipStream_t stream) {
    const float* feat = (const float*)d_in[0];   // (4,32,64,64)
    const float* outv = (const float*)d_in[1];   // (4,2,64,64)
    const float* w1   = (const float*)d_in[2];   // (2,32)
    const float* b1   = (const float*)d_in[3];   // (2,)
    const float* w2   = (const float*)d_in[4];   // (2,32)
    const float* b2   = (const float*)d_in[5];   // (2,)
    float* o = (float*)d_out;                    // (4,2,64,64)

    // workspace layout (512 KB total):
    float*  ws    = (float*)d_ws;
    float2* f1v   = (float2*)ws;                 // 16384 float2 = 128 KB
    float2* f2v   = (float2*)(ws + 32768);       // 16384 float2 = 128 KB
    float4* stats = (float4*)(ws + 65536);       // 16384 float4 = 256 KB

    proj_kernel<<<64, 256, 0, stream>>>(feat, w1, b1, w2, b2, f1v, f2v);
    rowstats_kernel<<<256, 256, 0, stream>>>(f1v, f2v, outv, stats);
    colout_kernel<<<256, 256, 0, stream>>>(f1v, f2v, stats, o);
}

// Round 2
// 60.999 us; speedup vs baseline: 2.5003x; 2.5003x over previous
//
#include <hip/hip_runtime.h>

#define HW   4096
#define CIN  32
// scale in log2 domain: (1/sqrt(NCLASS)) * log2(e); NCLASS = 2
#define SCALE2 (0.70710678118654752f * 1.44269504088896340f)

// ---------------- Kernel A: 1x1 conv projections, channel-split 4-way across waves
__global__ __launch_bounds__(256) void proj_kernel(
        const float* __restrict__ feat,
        const float* __restrict__ w1, const float* __restrict__ b1,
        const float* __restrict__ w2, const float* __restrict__ b2,
        float2* __restrict__ f1v, float2* __restrict__ f2v) {
    __shared__ float4 red[4][64];
    int tid = threadIdx.x;
    int pl = tid & 63;
    int cq = tid >> 6;                 // wave id = channel quarter
    int b = blockIdx.x;                // 256 blocks
    int n = b >> 6;
    int p = ((b & 63) << 6) + pl;
    const float* fbase = feat + ((size_t)n * CIN + cq * 8) * HW + p;
    float a10 = 0.f, a11 = 0.f, a20 = 0.f, a21 = 0.f;
#pragma unroll
    for (int c = 0; c < 8; ++c) {
        float v = fbase[(size_t)c * HW];
        a10 += v * w1[cq * 8 + c];
        a11 += v * w1[32 + cq * 8 + c];
        a20 += v * w2[cq * 8 + c];
        a21 += v * w2[32 + cq * 8 + c];
    }
    red[cq][pl] = make_float4(a10, a11, a20, a21);
    __syncthreads();
    if (tid < 64) {
        float4 r0 = red[0][tid], r1 = red[1][tid], r2 = red[2][tid], r3 = red[3][tid];
        int idx = n * HW + ((b & 63) << 6) + tid;
        f1v[idx] = make_float2(r0.x + r1.x + r2.x + r3.x + b1[0],
                               r0.y + r1.y + r2.y + r3.y + b1[1]);
        f2v[idx] = make_float2(r0.z + r1.z + r2.z + r3.z + b2[0],
                               r0.w + r1.w + r2.w + r3.w + b2[1]);
    }
}

// ---------------- Kernel B: l[p] = sum_q 2^(scale*dot); write {f1, V0/l, V1/l}
__global__ __launch_bounds__(256) void rowstats_kernel(
        const float2* __restrict__ f1v, const float2* __restrict__ f2v,
        const float* __restrict__ outv, float4* __restrict__ stats4) {
    __shared__ float red[4][8];
    int tid = threadIdx.x;
    int pl = tid & 7;
    int slice = tid >> 3;              // 32 slices of 128 q
    int b = blockIdx.x;                // 2048 blocks
    int n = b >> 9;
    int pg = b & 511;
    int p = (pg << 3) + pl;
    int base = n * HW;
    float2 f1p = f1v[base + p];
    float f10 = f1p.x * SCALE2, f11 = f1p.y * SCALE2;
    const float4* f2b = (const float4*)(f2v + base + slice * 128);
    float l0 = 0.f, l1 = 0.f;
#pragma unroll 4
    for (int i = 0; i < 64; ++i) {
        float4 ab = f2b[i];            // two q's per 16B load
        l0 += exp2f(f10 * ab.x + f11 * ab.y);
        l1 += exp2f(f10 * ab.z + f11 * ab.w);
    }
    float l = l0 + l1;
    l += __shfl_xor(l, 8);
    l += __shfl_xor(l, 16);
    l += __shfl_xor(l, 32);
    if ((tid & 63) < 8) red[tid >> 6][pl] = l;
    __syncthreads();
    if (tid < 8) {
        float lt = red[0][tid] + red[1][tid] + red[2][tid] + red[3][tid];
        float inv = 1.0f / lt;
        int pp = (pg << 3) + tid;
        float2 f1 = f1v[base + pp];
        float v0 = outv[(n * 2 + 0) * HW + pp];
        float v1 = outv[(n * 2 + 1) * HW + pp];
        stats4[base + pp] = make_float4(f1.x, f1.y, v0 * inv, v1 * inv);
    }
}

// ---------------- Kernel C: o[c,q] = sum_p (V[c,p]/l[p]) * 2^(scale*dot)
__global__ __launch_bounds__(256) void colout_kernel(
        const float2* __restrict__ f2v, const float4* __restrict__ stats4,
        float* __restrict__ o) {
    __shared__ float red[4][8][2];
    int tid = threadIdx.x;
    int ql = tid & 7;
    int slice = tid >> 3;              // 32 slices of 128 p
    int b = blockIdx.x;                // 2048 blocks
    int n = b >> 9;
    int qg = b & 511;
    int q = (qg << 3) + ql;
    int base = n * HW;
    float2 f2q = f2v[base + q];
    float g0 = f2q.x * SCALE2, g1 = f2q.y * SCALE2;
    const float4* stb = stats4 + base + slice * 128;
    float o0 = 0.f, o1 = 0.f;
#pragma unroll 4
    for (int i = 0; i < 128; ++i) {
        float4 s = stb[i];             // {f1.x, f1.y, V0/l, V1/l}
        float e = exp2f(g0 * s.x + g1 * s.y);
        o0 += s.z * e;
        o1 += s.w * e;
    }
    o0 += __shfl_xor(o0, 8);  o1 += __shfl_xor(o1, 8);
    o0 += __shfl_xor(o0, 16); o1 += __shfl_xor(o1, 16);
    o0 += __shfl_xor(o0, 32); o1 += __shfl_xor(o1, 32);
    if ((tid & 63) < 8) { red[tid >> 6][ql][0] = o0; red[tid >> 6][ql][1] = o1; }
    __syncthreads();
    if (tid < 16) {
        int qq = tid >> 1, c = tid & 1;
        float r = red[0][qq][c] + red[1][qq][c] + red[2][qq][c] + red[3][qq][c];
        o[(n * 2 + c) * HW + (qg << 3) + qq] = r;
    }
}

extern "C" void kernel_launch(void* const* d_in, const int* in_sizes, int n_in,
                              void* d_out, int out_size, void* d_ws, size_t ws_size,
                              hipStream_t stream) {
    const float* feat = (const float*)d_in[0];   // (4,32,64,64)
    const float* outv = (const float*)d_in[1];   // (4,2,64,64)
    const float* w1   = (const float*)d_in[2];   // (2,32)
    const float* b1   = (const float*)d_in[3];   // (2,)
    const float* w2   = (const float*)d_in[4];   // (2,32)
    const float* b2   = (const float*)d_in[5];   // (2,)
    float* o = (float*)d_out;                    // (4,2,64,64)

    // workspace layout (512 KB total):
    float*  ws     = (float*)d_ws;
    float2* f1v    = (float2*)ws;                // 16384 float2 = 128 KB
    float2* f2v    = (float2*)(ws + 32768);      // 16384 float2 = 128 KB
    float4* stats4 = (float4*)(ws + 65536);      // 16384 float4 = 256 KB

    proj_kernel<<<256, 256, 0, stream>>>(feat, w1, b1, w2, b2, f1v, f2v);
    rowstats_kernel<<<2048, 256, 0, stream>>>(f1v, f2v, outv, stats4);
    colout_kernel<<<2048, 256, 0, stream>>>(f2v, stats4, o);
}

// Round 3
// 57.176 us; speedup vs baseline: 2.6675x; 1.0669x over previous
//
#include <hip/hip_runtime.h>

#define HW   4096
#define CIN  32
// scale in log2 domain: (1/sqrt(NCLASS)) * log2(e); NCLASS = 2
#define SCALE2 (0.70710678118654752f * 1.44269504088896340f)

// Raw v_exp_f32 (2^x). Args here are bounded (|x| ~< 10), so the libm
// denormal-fixup sequence exp2f() drags in is dead weight.
__device__ __forceinline__ float exp2_raw(float x) {
#if __has_builtin(__builtin_amdgcn_exp2f)
    return __builtin_amdgcn_exp2f(x);
#else
    float r;
    asm("v_exp_f32 %0, %1" : "=v"(r) : "v"(x));
    return r;
#endif
}

// ---------------- Kernel A: 1x1 conv projections, channel-split 4-way across waves
__global__ __launch_bounds__(256) void proj_kernel(
        const float* __restrict__ feat,
        const float* __restrict__ w1, const float* __restrict__ b1,
        const float* __restrict__ w2, const float* __restrict__ b2,
        float2* __restrict__ f1v, float2* __restrict__ f2v) {
    __shared__ float4 red[4][64];
    int tid = threadIdx.x;
    int pl = tid & 63;
    int cq = tid >> 6;                 // wave id = channel quarter
    int b = blockIdx.x;                // 256 blocks
    int n = b >> 6;
    int p = ((b & 63) << 6) + pl;
    const float* fbase = feat + ((size_t)n * CIN + cq * 8) * HW + p;
    float a10 = 0.f, a11 = 0.f, a20 = 0.f, a21 = 0.f;
#pragma unroll
    for (int c = 0; c < 8; ++c) {
        float v = fbase[(size_t)c * HW];
        a10 += v * w1[cq * 8 + c];
        a11 += v * w1[32 + cq * 8 + c];
        a20 += v * w2[cq * 8 + c];
        a21 += v * w2[32 + cq * 8 + c];
    }
    red[cq][pl] = make_float4(a10, a11, a20, a21);
    __syncthreads();
    if (tid < 64) {
        float4 r0 = red[0][tid], r1 = red[1][tid], r2 = red[2][tid], r3 = red[3][tid];
        int idx = n * HW + ((b & 63) << 6) + tid;
        f1v[idx] = make_float2(r0.x + r1.x + r2.x + r3.x + b1[0],
                               r0.y + r1.y + r2.y + r3.y + b1[1]);
        f2v[idx] = make_float2(r0.z + r1.z + r2.z + r3.z + b2[0],
                               r0.w + r1.w + r2.w + r3.w + b2[1]);
    }
}

// ---------------- Kernel B: l[p] = sum_q 2^(scale*dot); write {f1, V0/l, V1/l}
__global__ __launch_bounds__(256, 8) void rowstats_kernel(
        const float2* __restrict__ f1v, const float2* __restrict__ f2v,
        const float* __restrict__ outv, float4* __restrict__ stats4) {
    __shared__ float red[4][8];
    int tid = threadIdx.x;
    int pl = tid & 7;
    int slice = tid >> 3;              // 32 slices, strided by 32 over q-pairs
    int b = blockIdx.x;                // 2048 blocks
    int n = b >> 9;
    int pg = b & 511;
    int p = (pg << 3) + pl;
    int base = n * HW;
    float2 f1p = f1v[base + p];
    float f10 = f1p.x * SCALE2, f11 = f1p.y * SCALE2;
    const float4* f2b = (const float4*)(f2v + base);   // 2048 float4 (q-pairs)
    float l0 = 0.f, l1 = 0.f;
#pragma unroll 4
    for (int i = 0; i < 64; ++i) {
        float4 ab = f2b[slice + 32 * i];   // coalesced across slices in a wave
        float ta = f10 * ab.x + f11 * ab.y;
        float tb = f10 * ab.z + f11 * ab.w;
        l0 += exp2_raw(ta);
        l1 += exp2_raw(tb);
    }
    float l = l0 + l1;
    l += __shfl_xor(l, 8);
    l += __shfl_xor(l, 16);
    l += __shfl_xor(l, 32);
    if ((tid & 63) < 8) red[tid >> 6][pl] = l;
    __syncthreads();
    if (tid < 8) {
        float lt = red[0][tid] + red[1][tid] + red[2][tid] + red[3][tid];
        float inv = 1.0f / lt;
        int pp = (pg << 3) + tid;
        float2 f1 = f1v[base + pp];
        float v0 = outv[(n * 2 + 0) * HW + pp];
        float v1 = outv[(n * 2 + 1) * HW + pp];
        stats4[base + pp] = make_float4(f1.x * SCALE2, f1.y * SCALE2, v0 * inv, v1 * inv);
    }
}

// ---------------- Kernel C: o[c,q] = sum_p (V[c,p]/l[p]) * 2^(scale*dot)
__global__ __launch_bounds__(256, 8) void colout_kernel(
        const float2* __restrict__ f2v, const float4* __restrict__ stats4,
        float* __restrict__ o) {
    __shared__ float red[4][8][2];
    int tid = threadIdx.x;
    int ql = tid & 7;
    int slice = tid >> 3;              // 32 slices, strided by 32 over p
    int b = blockIdx.x;                // 2048 blocks
    int n = b >> 9;
    int qg = b & 511;
    int q = (qg << 3) + ql;
    int base = n * HW;
    float2 f2q = f2v[base + q];
    float g0 = f2q.x, g1 = f2q.y;      // SCALE2 pre-folded into stats4 f1
    const float4* stb = stats4 + base;
    float o00 = 0.f, o01 = 0.f, o10 = 0.f, o11 = 0.f;
#pragma unroll 2
    for (int i = 0; i < 128; i += 2) {
        float4 sa = stb[slice + 32 * i];         // {f1x*s, f1y*s, V0/l, V1/l}
        float4 sb = stb[slice + 32 * (i + 1)];
        float ea = exp2_raw(g0 * sa.x + g1 * sa.y);
        float eb = exp2_raw(g0 * sb.x + g1 * sb.y);
        o00 += sa.z * ea;
        o01 += sa.w * ea;
        o10 += sb.z * eb;
        o11 += sb.w * eb;
    }
    float o0 = o00 + o10, o1 = o01 + o11;
    o0 += __shfl_xor(o0, 8);  o1 += __shfl_xor(o1, 8);
    o0 += __shfl_xor(o0, 16); o1 += __shfl_xor(o1, 16);
    o0 += __shfl_xor(o0, 32); o1 += __shfl_xor(o1, 32);
    if ((tid & 63) < 8) { red[tid >> 6][ql][0] = o0; red[tid >> 6][ql][1] = o1; }
    __syncthreads();
    if (tid < 16) {
        int qq = tid >> 1, c = tid & 1;
        float r = red[0][qq][c] + red[1][qq][c] + red[2][qq][c] + red[3][qq][c];
        o[(n * 2 + c) * HW + (qg << 3) + qq] = r;
    }
}

extern "C" void kernel_launch(void* const* d_in, const int* in_sizes, int n_in,
                              void* d_out, int out_size, void* d_ws, size_t ws_size,
                              hipStream_t stream) {
    const float* feat = (const float*)d_in[0];   // (4,32,64,64)
    const float* outv = (const float*)d_in[1];   // (4,2,64,64)
    const float* w1   = (const float*)d_in[2];   // (2,32)
    const float* b1   = (const float*)d_in[3];   // (2,)
    const float* w2   = (const float*)d_in[4];   // (2,32)
    const float* b2   = (const float*)d_in[5];   // (2,)
    float* o = (float*)d_out;                    // (4,2,64,64)

    // workspace layout (512 KB used):
    float*  ws     = (float*)d_ws;
    float2* f1v    = (float2*)ws;                // 16384 float2 = 128 KB
    float2* f2v    = (float2*)(ws + 32768);      // 16384 float2 = 128 KB
    float4* stats4 = (float4*)(ws + 65536);      // 16384 float4 = 256 KB

    proj_kernel<<<256, 256, 0, stream>>>(feat, w1, b1, w2, b2, f1v, f2v);
    rowstats_kernel<<<2048, 256, 0, stream>>>(f1v, f2v, outv, stats4);
    colout_kernel<<<2048, 256, 0, stream>>>(f2v, stats4, o);
}

// Round 4
// 35.665 us; speedup vs baseline: 4.2764x; 1.6031x over previous
//
#include <hip/hip_runtime.h>

#define HW   4096
#define CIN  32
// scale in log2 domain: (1/sqrt(NCLASS)) * log2(e); NCLASS = 2
#define SCALE2 (0.70710678118654752f * 1.44269504088896340f)

// Raw v_exp_f32 (2^x): args bounded (|x| <~ 8), skip libm denormal fixup.
__device__ __forceinline__ float exp2_raw(float x) {
#if __has_builtin(__builtin_amdgcn_exp2f)
    return __builtin_amdgcn_exp2f(x);
#else
    float r;
    asm("v_exp_f32 %0, %1" : "=v"(r) : "v"(x));
    return r;
#endif
}

// ---------------- Kernel A: 1x1 conv projections, channel-split 4-way across waves
__global__ __launch_bounds__(256) void proj_kernel(
        const float* __restrict__ feat,
        const float* __restrict__ w1, const float* __restrict__ b1,
        const float* __restrict__ w2, const float* __restrict__ b2,
        float2* __restrict__ f1v, float2* __restrict__ f2v) {
    __shared__ float4 red[4][64];
    int tid = threadIdx.x;
    int pl = tid & 63;
    int cq = tid >> 6;                 // wave id = channel quarter
    int b = blockIdx.x;                // 256 blocks
    int n = b >> 6;
    int p = ((b & 63) << 6) + pl;
    const float* fbase = feat + ((size_t)n * CIN + cq * 8) * HW + p;
    float a10 = 0.f, a11 = 0.f, a20 = 0.f, a21 = 0.f;
#pragma unroll
    for (int c = 0; c < 8; ++c) {
        float v = fbase[(size_t)c * HW];
        a10 += v * w1[cq * 8 + c];
        a11 += v * w1[32 + cq * 8 + c];
        a20 += v * w2[cq * 8 + c];
        a21 += v * w2[32 + cq * 8 + c];
    }
    red[cq][pl] = make_float4(a10, a11, a20, a21);
    __syncthreads();
    if (tid < 64) {
        float4 r0 = red[0][tid], r1 = red[1][tid], r2 = red[2][tid], r3 = red[3][tid];
        int idx = n * HW + ((b & 63) << 6) + tid;
        f1v[idx] = make_float2(r0.x + r1.x + r2.x + r3.x + b1[0],
                               r0.y + r1.y + r2.y + r3.y + b1[1]);
        f2v[idx] = make_float2(r0.z + r1.z + r2.z + r3.z + b2[0],
                               r0.w + r1.w + r2.w + r3.w + b2[1]);
    }
}

// ---------------- Kernel B: l[p] = sum_q 2^(scale*dot); write {f1*s, V0/l, V1/l}
// block b: n = b>>9, 8 p's = (b&511)*8..+8 (f1 uniform -> SGPRs).
// wave w streams q in [w*1024, w*1024+1024) as float4 (2 q per lane), coalesced.
__global__ __launch_bounds__(256, 8) void rowstats_kernel(
        const float2* __restrict__ f1v, const float2* __restrict__ f2v,
        const float* __restrict__ outv, float4* __restrict__ stats4) {
    __shared__ float red[4][8];
    int tid = threadIdx.x;
    int lane = tid & 63;
    int wid = tid >> 6;
    int b = blockIdx.x;                // 2048 blocks
    int n = b >> 9;
    int pg = (b & 511) << 3;
    int base = n * HW;

    float f10[8], f11[8];
#pragma unroll
    for (int j = 0; j < 8; ++j) {      // uniform index -> s_load
        float2 f1 = f1v[base + pg + j];
        f10[j] = f1.x * SCALE2;
        f11[j] = f1.y * SCALE2;
    }
    const float4* f2b = (const float4*)(f2v + base) + wid * 512 + lane;
    float acc[8];
#pragma unroll
    for (int j = 0; j < 8; ++j) acc[j] = 0.f;
#pragma unroll 2
    for (int s = 0; s < 8; ++s) {
        float4 ab = f2b[s * 64];       // 1 KB unique per wave-load
#pragma unroll
        for (int j = 0; j < 8; ++j) {
            float e0 = exp2_raw(f10[j] * ab.x + f11[j] * ab.y);
            float e1 = exp2_raw(f10[j] * ab.z + f11[j] * ab.w);
            acc[j] += e0 + e1;
        }
    }
#pragma unroll
    for (int j = 0; j < 8; ++j) {
        float a = acc[j];
        a += __shfl_xor(a, 1);  a += __shfl_xor(a, 2);
        a += __shfl_xor(a, 4);  a += __shfl_xor(a, 8);
        a += __shfl_xor(a, 16); a += __shfl_xor(a, 32);
        acc[j] = a;
    }
    if (lane == 0) {
#pragma unroll
        for (int j = 0; j < 8; ++j) red[wid][j] = acc[j];
    }
    __syncthreads();
    if (tid < 8) {
        float lt = red[0][tid] + red[1][tid] + red[2][tid] + red[3][tid];
        float inv = 1.0f / lt;
        int pp = pg + tid;
        float2 f1 = f1v[base + pp];
        float v0 = outv[(n * 2 + 0) * HW + pp];
        float v1 = outv[(n * 2 + 1) * HW + pp];
        stats4[base + pp] = make_float4(f1.x * SCALE2, f1.y * SCALE2, v0 * inv, v1 * inv);
    }
}

// ---------------- Kernel C: o[c,q] = sum_p (V[c,p]/l[p]) * 2^(scale*dot)
// block b: n = b>>9, 8 q's = (b&511)*8..+8 (f2 uniform -> SGPRs).
// wave w streams p in [w*1024, w*1024+1024), one stats4 entry per lane, coalesced.
__global__ __launch_bounds__(256, 8) void colout_kernel(
        const float2* __restrict__ f2v, const float4* __restrict__ stats4,
        float* __restrict__ o) {
    __shared__ float red[4][8][2];
    int tid = threadIdx.x;
    int lane = tid & 63;
    int wid = tid >> 6;
    int b = blockIdx.x;                // 2048 blocks
    int n = b >> 9;
    int qg = (b & 511) << 3;
    int base = n * HW;

    float g0[8], g1[8];
#pragma unroll
    for (int j = 0; j < 8; ++j) {      // uniform index -> s_load
        float2 f2 = f2v[base + qg + j];
        g0[j] = f2.x;                  // SCALE2 folded into stats4 f1
        g1[j] = f2.y;
    }
    const float4* stb = stats4 + base + wid * 1024 + lane;
    float o0[8], o1[8];
#pragma unroll
    for (int j = 0; j < 8; ++j) { o0[j] = 0.f; o1[j] = 0.f; }
#pragma unroll 2
    for (int s = 0; s < 16; ++s) {
        float4 st = stb[s * 64];       // {f1x*s, f1y*s, V0/l, V1/l}, 1 KB unique
#pragma unroll
        for (int j = 0; j < 8; ++j) {
            float e = exp2_raw(g0[j] * st.x + g1[j] * st.y);
            o0[j] += st.z * e;
            o1[j] += st.w * e;
        }
    }
#pragma unroll
    for (int j = 0; j < 8; ++j) {
        float a = o0[j], c = o1[j];
        a += __shfl_xor(a, 1);  c += __shfl_xor(c, 1);
        a += __shfl_xor(a, 2);  c += __shfl_xor(c, 2);
        a += __shfl_xor(a, 4);  c += __shfl_xor(c, 4);
        a += __shfl_xor(a, 8);  c += __shfl_xor(c, 8);
        a += __shfl_xor(a, 16); c += __shfl_xor(c, 16);
        a += __shfl_xor(a, 32); c += __shfl_xor(c, 32);
        o0[j] = a; o1[j] = c;
    }
    if (lane == 0) {
#pragma unroll
        for (int j = 0; j < 8; ++j) { red[wid][j][0] = o0[j]; red[wid][j][1] = o1[j]; }
    }
    __syncthreads();
    if (tid < 16) {
        int qq = tid >> 1, c = tid & 1;
        float r = red[0][qq][c] + red[1][qq][c] + red[2][qq][c] + red[3][qq][c];
        o[(n * 2 + c) * HW + qg + qq] = r;
    }
}

extern "C" void kernel_launch(void* const* d_in, const int* in_sizes, int n_in,
                              void* d_out, int out_size, void* d_ws, size_t ws_size,
                              hipStream_t stream) {
    const float* feat = (const float*)d_in[0];   // (4,32,64,64)
    const float* outv = (const float*)d_in[1];   // (4,2,64,64)
    const float* w1   = (const float*)d_in[2];   // (2,32)
    const float* b1   = (const float*)d_in[3];   // (2,)
    const float* w2   = (const float*)d_in[4];   // (2,32)
    const float* b2   = (const float*)d_in[5];   // (2,)
    float* o = (float*)d_out;                    // (4,2,64,64)

    // workspace layout (512 KB used):
    float*  ws     = (float*)d_ws;
    float2* f1v    = (float2*)ws;                // 16384 float2 = 128 KB
    float2* f2v    = (float2*)(ws + 32768);      // 16384 float2 = 128 KB
    float4* stats4 = (float4*)(ws + 65536);      // 16384 float4 = 256 KB

    proj_kernel<<<256, 256, 0, stream>>>(feat, w1, b1, w2, b2, f1v, f2v);
    rowstats_kernel<<<2048, 256, 0, stream>>>(f1v, f2v, outv, stats4);
    colout_kernel<<<2048, 256, 0, stream>>>(f2v, stats4, o);
}